// Round 22
// baseline (63.799 us; speedup 1.0000x reference)
//
#include <hip/hip_runtime.h>

#define T_LEN 4096
#define D_IN 128
#define U_H 256
#define REC_MAXV 0.0625f
#define SC1 0x7F7F7F7F   // e8m0 scale bytes: 127 -> 2^0 = 1.0

typedef __attribute__((ext_vector_type(4))) float f32x4;
typedef __attribute__((ext_vector_type(16))) float f32x16;
typedef __attribute__((ext_vector_type(2))) int int2v;
typedef __attribute__((ext_vector_type(8))) int int8v;

template <bool HI>
__device__ __forceinline__ int pk8(float a, float b, int old) {
    return __builtin_amdgcn_cvt_pk_fp8_f32(a, b, old, HI);
}

__device__ __forceinline__ int reord32(int u) {
    int r = u & 31;
    return ((u >> 5) << 5) + (((r >> 2) & 1) << 4) + ((r >> 3) << 2) + (r & 3);
}

// -------- kernel 0 (fused prep): h, budR, boR, fp8 K=64 frags, loss0 ---------
// Frag layout (A-operand of mfma_scale_32x32x64, 2KB/frag, 4 x 512B slots):
//   frag f, lane l, operand int r (0..7): bytes = k = (l>>5)*32 + 4r + 0..3
//   stored at f*2048 + (r>>1)*512 + l*8 + (r&1)*4  (b64 reads stride-8: free)
// Wd frags f = uw*2+w (uw 0..7 = 32-u row window, w 0..1 = 64-k window)
// Wo frags f2 = dw*4+uwin (dw 0..3 = 32-d rows, uwin 0..3 = 64-u k-window)
__global__ void k_pre(const float* __restrict__ xs, const float* __restrict__ We,
                      const float* __restrict__ be, const float* __restrict__ Wd,
                      const float* __restrict__ bd, const float* __restrict__ ud,
                      const float* __restrict__ Wo, const float* __restrict__ bo,
                      float* __restrict__ budR, float* __restrict__ boR,
                      char* __restrict__ WF8, float* __restrict__ part2) {
    __shared__ __align__(16) float hL[256];
    __shared__ float red[2];
    const int b = blockIdx.x, u = threadIdx.x;

    const f32x4* xr = (const f32x4*)(xs + ((size_t)b * T_LEN + (T_LEN - 1)) * D_IN);
    const f32x4* wr = (const f32x4*)(We + (size_t)u * D_IN);
    float s = 0.f;
#pragma unroll
    for (int i = 0; i < 32; ++i) {
        f32x4 a = xr[i], w = wr[i];
        s += a[0]*w[0] + a[1]*w[1] + a[2]*w[2] + a[3]*w[3];
    }
    s += be[u];
    s = fmaxf(s, 0.f);
    hL[u] = s;

    float udc = fminf(fmaxf(ud[u], -REC_MAXV), REC_MAXV);
    budR[(b << 8) + reord32(u)] = bd[u] + udc * s;

    if (b == 0 && u < 128) boR[reord32(u)] = bo[u];

    int gid = b * 256 + u;            // 0..16383, one packed int each
    if (gid < 8192) {
        int f = gid >> 9, l = (gid >> 3) & 63, r = gid & 7;
        int uw = f >> 1, w = f & 1;
        const float* src = Wd + (size_t)(uw * 32 + (l & 31)) * D_IN
                              + w * 64 + (l >> 5) * 32 + r * 4;
        int v = pk8<false>(src[0], src[1], 0); v = pk8<true>(src[2], src[3], v);
        *(int*)(WF8 + ((size_t)f << 11) + ((r >> 1) << 9) + (l << 3) + ((r & 1) << 2)) = v;
    } else {
        int g = gid - 8192;
        int f = g >> 9, l = (g >> 3) & 63, r = g & 7;
        int dw = f >> 2, uwin = f & 3;
        const float* src = Wo + (size_t)(dw * 32 + (l & 31)) * U_H
                              + uwin * 64 + (l >> 5) * 32 + r * 4;
        int v = pk8<false>(src[0], src[1], 0); v = pk8<true>(src[2], src[3], v);
        *(int*)(WF8 + 32768 + ((size_t)f << 11) + ((r >> 1) << 9) + (l << 3) + ((r & 1) << 2)) = v;
    }
    __syncthreads();

    float v = 0.f;
    if (u < 128) {
        const f32x4* hr = (const f32x4*)hL;
        const f32x4* wo = (const f32x4*)(Wo + (size_t)u * U_H);
        float s2 = 0.f;
#pragma unroll
        for (int i = 0; i < 64; ++i) {
            f32x4 a = hr[i], w = wo[i];
            s2 += a[0]*w[0] + a[1]*w[1] + a[2]*w[2] + a[3]*w[3];
        }
        s2 += bo[u];
        float x = xs[((size_t)b * T_LEN + T_LEN - 1) * D_IN + u];
        float diff = x - s2;
        v = diff * diff;
    }
#pragma unroll
    for (int o = 32; o > 0; o >>= 1) v += __shfl_down(v, o);
    if (u == 0) red[0] = v;
    if (u == 64) red[1] = v;
    __syncthreads();
    if (u == 0) part2[b] = red[0] + red[1];
}

__device__ __forceinline__ int8v ldfrag(const char* p) {
    int2v t0 = *(const int2v*)(p);
    int2v t1 = *(const int2v*)(p + 512);
    int2v t2 = *(const int2v*)(p + 1024);
    int2v t3 = *(const int2v*)(p + 1536);
    int8v a;
    a[0] = t0[0]; a[1] = t0[1]; a[2] = t1[0]; a[3] = t1[1];
    a[4] = t2[0]; a[5] = t2[1]; a[6] = t3[0]; a[7] = t3[1];
    return a;
}

// ---- ph1 for one 32-u window uw: 2 x K=64 scaled MFMA (bias in C-init),
// relu, pack to the FULL-32-u per-lane fp8 vector (ascending u; both hi
// halves identical) via 4 permlane32_swap self-swaps + constant-idx selects.
__device__ __forceinline__ int8v ph1s(const char* lds, const float* budL,
                                      int lane, int hi, int uw,
                                      int8v xw0, int8v xw1) {
    f32x16 c;
    {
        const float* bp = budL + uw * 32 + hi * 16;
        f32x4 b0 = *(const f32x4*)(bp), b1 = *(const f32x4*)(bp + 4);
        f32x4 b2 = *(const f32x4*)(bp + 8), b3 = *(const f32x4*)(bp + 12);
        c[0]=b0[0]; c[1]=b0[1]; c[2]=b0[2]; c[3]=b0[3];
        c[4]=b1[0]; c[5]=b1[1]; c[6]=b1[2]; c[7]=b1[3];
        c[8]=b2[0]; c[9]=b2[1]; c[10]=b2[2]; c[11]=b2[3];
        c[12]=b3[0]; c[13]=b3[1]; c[14]=b3[2]; c[15]=b3[3];
    }
    int8v a0 = ldfrag(lds + ((size_t)(uw * 2 + 0) << 11) + (lane << 3));
    int8v a1 = ldfrag(lds + ((size_t)(uw * 2 + 1) << 11) + (lane << 3));
    c = __builtin_amdgcn_mfma_scale_f32_32x32x64_f8f6f4(a0, xw0, c, 0, 0, 0, SC1, 0, SC1);
    c = __builtin_amdgcn_mfma_scale_f32_32x32x64_f8f6f4(a1, xw1, c, 0, 0, 0, SC1, 0, SC1);
#pragma unroll
    for (int i = 0; i < 16; ++i) c[i] = fmaxf(c[i], 0.f);
    int8v p;
#pragma unroll
    for (int q = 0; q < 4; ++q) {
        int own = pk8<false>(c[4*q], c[4*q+1], 0);
        own = pk8<true>(c[4*q+2], c[4*q+3], own);
        int2v sw = __builtin_amdgcn_permlane32_swap(own, own, false, false);
        int partner = hi ? sw[0] : sw[1];
        p[2*q]     = hi ? partner : own;   // slot for source-half hi'=0
        p[2*q + 1] = hi ? own : partner;   // slot for source-half hi'=1
    }
    return p;
}

// ---------------- kernel 1: main pipeline, MX-scaled K=64 fp8 ----------------
// 1024 blocks x 512 threads (8 waves), 1 tile (32 rows)/wave. Per uw-pair:
// 2x2 ph1 MFMA + 4 ph2 MFMA (total 32/tile vs 128 K=16 ones): MFMA issue
// halved, dependency chains 4x shorter. Scales fixed at 1.0 (SC1).
__global__ __launch_bounds__(512, 2) void k_main(
        const float* __restrict__ xs, const float* __restrict__ budR,
        const float* __restrict__ boR, const char* __restrict__ WF8,
        float* __restrict__ part) {
    __shared__ __align__(16) char lds[67200];
    const int tid = threadIdx.x;

    for (int i = tid; i < 4096; i += 512)
        ((f32x4*)lds)[i] = ((const f32x4*)WF8)[i];
    const int b = blockIdx.x >> 4;          // 16 blocks per batch-entry
    if (tid < 64) ((f32x4*)(lds + 65536))[tid] = ((const f32x4*)(budR + b * 256))[tid];
    else if (tid < 96) ((f32x4*)(lds + 66560))[tid - 64] = ((const f32x4*)boR)[tid - 64];
    __syncthreads();

    const int wave = tid >> 6, lane = tid & 63;
    const int m = lane & 31, hi = lane >> 5;
    const float* xsb = xs + ((size_t)b << 19);
    const float* budL = (const float*)(lds + 65536);
    const float* boL  = (const float*)(lds + 66560);
    float* wsumf = (float*)(lds + 67072);

    const int tile = blockIdx.x * 8 + wave;
    const int t0 = (tile & 127) << 5;

    // ---- X row -> two K=64 B-operand windows (int8v each) ----
    const float* xb0 = xsb + (size_t)(t0 + m) * 128 + hi * 32;
    int8v xw0, xw1;
#pragma unroll
    for (int r = 0; r < 8; ++r) {
        f32x4 v0 = *(const f32x4*)(xb0 + r * 4);
        int t = pk8<false>(v0[0], v0[1], 0); t = pk8<true>(v0[2], v0[3], t);
        xw0[r] = t;
        f32x4 v1 = *(const f32x4*)(xb0 + 64 + r * 4);
        int t2 = pk8<false>(v1[0], v1[1], 0); t2 = pk8<true>(v1[2], v1[3], t2);
        xw1[r] = t2;
    }

    // ---- o accumulators init from boR (bo folded into GEMM2 C-init) ----
    f32x16 o0, o1, o2, o3;
#define OINIT(OV, DT)                                                    \
    {   const float* bp = boL + (DT) * 32 + hi * 16;                     \
        f32x4 b0 = *(const f32x4*)(bp), b1 = *(const f32x4*)(bp + 4);    \
        f32x4 b2 = *(const f32x4*)(bp + 8), b3 = *(const f32x4*)(bp + 12); \
        OV[0]=b0[0]; OV[1]=b0[1]; OV[2]=b0[2]; OV[3]=b0[3];              \
        OV[4]=b1[0]; OV[5]=b1[1]; OV[6]=b1[2]; OV[7]=b1[3];              \
        OV[8]=b2[0]; OV[9]=b2[1]; OV[10]=b2[2]; OV[11]=b2[3];            \
        OV[12]=b3[0]; OV[13]=b3[1]; OV[14]=b3[2]; OV[15]=b3[3]; }
    OINIT(o0, 0) OINIT(o1, 1) OINIT(o2, 2) OINIT(o3, 3)
#undef OINIT

    // ---- rolled loop over uw pairs ----
#pragma clang loop unroll(disable)
    for (int pr = 0; pr < 4; ++pr) {
        int8v ep = ph1s(lds, budL, lane, hi, 2 * pr, xw0, xw1);
        int8v op = ph1s(lds, budL, lane, hi, 2 * pr + 1, xw0, xw1);
        int8v decR;
#pragma unroll
        for (int r = 0; r < 8; ++r) decR[r] = hi ? op[r] : ep[r];
        const char* wo2 = lds + 32768 + (lane << 3);
        int8v w0 = ldfrag(wo2 + ((size_t)(0 * 4 + pr) << 11));
        int8v w1 = ldfrag(wo2 + ((size_t)(1 * 4 + pr) << 11));
        int8v w2 = ldfrag(wo2 + ((size_t)(2 * 4 + pr) << 11));
        int8v w3 = ldfrag(wo2 + ((size_t)(3 * 4 + pr) << 11));
        o0 = __builtin_amdgcn_mfma_scale_f32_32x32x64_f8f6f4(w0, decR, o0, 0, 0, 0, SC1, 0, SC1);
        o1 = __builtin_amdgcn_mfma_scale_f32_32x32x64_f8f6f4(w1, decR, o1, 0, 0, 0, SC1, 0, SC1);
        o2 = __builtin_amdgcn_mfma_scale_f32_32x32x64_f8f6f4(w2, decR, o2, 0, 0, 0, SC1, 0, SC1);
        o3 = __builtin_amdgcn_mfma_scale_f32_32x32x64_f8f6f4(w3, decR, o3, 0, 0, 0, SC1, 0, SC1);
    }

    // ---- fused loss epilogue (bo already inside o) ----
    const int t = t0 + m;
    const float sel = (t > 0) ? 1.f : 0.f;
    const float* trow = xsb + (size_t)((t > 0) ? t - 1 : 0) * 128;
    float lacc = 0.f;
#define EPI(OV, DT)                                                      \
    {   _Pragma("unroll")                                                \
        for (int q = 0; q < 4; ++q) {                                    \
            f32x4 tg = *(const f32x4*)(trow + (DT) * 32 + q * 8 + hi * 4); \
            _Pragma("unroll")                                            \
            for (int j = 0; j < 4; ++j) {                                \
                float diff = tg[j] - OV[q * 4 + j];                      \
                lacc += sel * diff * diff;                               \
            }                                                            \
        }                                                                \
    }
    EPI(o0, 0) EPI(o1, 1) EPI(o2, 2) EPI(o3, 3)
#undef EPI

    // ---- block-level reduction: ONE store per block, no atomic ----
#pragma unroll
    for (int o = 32; o > 0; o >>= 1) lacc += __shfl_down(lacc, o);
    if (lane == 0) wsumf[wave] = lacc;
    __syncthreads();
    if (tid == 0) {
        float s = 0.f;
#pragma unroll
        for (int i = 0; i < 8; ++i) s += wsumf[i];
        part[blockIdx.x] = s;
    }
}

// ---------------- kernel 2: final reduction (plain store, no atomic) ---------
__global__ void k_final(const float* __restrict__ part, const float* __restrict__ part2,
                        float* __restrict__ loss) {
    __shared__ float ws[16];
    const int tid = threadIdx.x;   // 1024
    float v = part[tid];
    if (tid < 64) v += part2[tid];
#pragma unroll
    for (int o = 32; o > 0; o >>= 1) v += __shfl_down(v, o);
    if ((tid & 63) == 0) ws[tid >> 6] = v;
    __syncthreads();
    if (tid == 0) {
        float s = 0.f;
#pragma unroll
        for (int i = 0; i < 16; ++i) s += ws[i];
        *loss = s * (1.f / 262144.f);
    }
}

extern "C" void kernel_launch(void* const* d_in, const int* in_sizes, int n_in,
                              void* d_out, int out_size, void* d_ws, size_t ws_size,
                              hipStream_t stream) {
    const float* xs = (const float*)d_in[0];
    const float* We = (const float*)d_in[1];
    const float* be = (const float*)d_in[2];
    // d_in[3] = ue (unused: encoder hidden state is always zero)
    const float* Wd = (const float*)d_in[4];
    const float* bd = (const float*)d_in[5];
    const float* ud = (const float*)d_in[6];
    const float* Wo = (const float*)d_in[7];
    const float* bo = (const float*)d_in[8];
    float* loss = (float*)d_out;

    char* ws = (char*)d_ws;
    float* budR  = (float*)(ws);             // 65536 B
    char*  WF8   = (char*)(ws + 65536);      // 65536 B
    float* boR   = (float*)(ws + 131072);    // 512 B
    float* part  = (float*)(ws + 131584);    // 4096 B (1024 block partials)
    float* part2 = (float*)(ws + 135680);    // 256 B  (64 loss0 partials)

    k_pre<<<64, 256, 0, stream>>>(xs, We, be, Wd, bd, ud, Wo, bo,
                                  budR, boR, WF8, part2);
    k_main<<<1024, 512, 0, stream>>>(xs, budR, boR, WF8, part);
    k_final<<<1, 1024, 0, stream>>>(part, part2, loss);
}

// Round 23
// 59.907 us; speedup vs baseline: 1.0650x; 1.0650x over previous
//
#include <hip/hip_runtime.h>

#define T_LEN 4096
#define D_IN 128
#define U_H 256
#define REC_MAXV 0.0625f

typedef __attribute__((ext_vector_type(4))) float f32x4;
typedef __attribute__((ext_vector_type(16))) float f32x16;
typedef __attribute__((ext_vector_type(2))) int int2v;
typedef long long i64;

template <bool HI>
__device__ __forceinline__ int pk8(float a, float b, int old) {
    return __builtin_amdgcn_cvt_pk_fp8_f32(a, b, old, HI);
}

__device__ __forceinline__ int reord32(int u) {
    int r = u & 31;
    return ((u >> 5) << 5) + (((r >> 2) & 1) << 4) + ((r >> 3) << 2) + (r & 3);
}

// -------- kernel 0 (fused prep): h, budR, boR, fp8 weight frags, loss0 -------
__global__ void k_pre(const float* __restrict__ xs, const float* __restrict__ We,
                      const float* __restrict__ be, const float* __restrict__ Wd,
                      const float* __restrict__ bd, const float* __restrict__ ud,
                      const float* __restrict__ Wo, const float* __restrict__ bo,
                      float* __restrict__ budR, float* __restrict__ boR,
                      char* __restrict__ WF8, float* __restrict__ part2) {
    __shared__ __align__(16) float hL[256];
    __shared__ float red[2];
    const int b = blockIdx.x, u = threadIdx.x;

    const f32x4* xr = (const f32x4*)(xs + ((size_t)b * T_LEN + (T_LEN - 1)) * D_IN);
    const f32x4* wr = (const f32x4*)(We + (size_t)u * D_IN);
    float s = 0.f;
#pragma unroll
    for (int i = 0; i < 32; ++i) {
        f32x4 a = xr[i], w = wr[i];
        s += a[0]*w[0] + a[1]*w[1] + a[2]*w[2] + a[3]*w[3];
    }
    s += be[u];
    s = fmaxf(s, 0.f);
    hL[u] = s;

    float udc = fminf(fmaxf(ud[u], -REC_MAXV), REC_MAXV);
    budR[(b << 8) + reord32(u)] = bd[u] + udc * s;

    if (b == 0 && u < 128) boR[reord32(u)] = bo[u];

    int gid = b * 256 + u;
    if (gid < 4096) {
        int f = gid >> 6, l = gid & 63;
        int ut = f >> 3, ks = f & 7;
        const float* src = Wd + (size_t)(ut * 32 + (l & 31)) * D_IN + ks * 16 + (l >> 5) * 8;
        int lo = pk8<false>(src[0], src[1], 0); lo = pk8<true>(src[2], src[3], lo);
        int hh = pk8<false>(src[4], src[5], 0); hh = pk8<true>(src[6], src[7], hh);
        *(int2v*)(WF8 + (size_t)gid * 8) = (int2v){lo, hh};
    } else if (gid < 8192) {
        int g = gid - 4096;
        int f = g >> 6, l = g & 63;
        int uk = f >> 2, dt = f & 3;
        const float* src = Wo + (size_t)(dt * 32 + (l & 31)) * U_H + uk * 16 + (l >> 5) * 8;
        int lo = pk8<false>(src[0], src[1], 0); lo = pk8<true>(src[2], src[3], lo);
        int hh = pk8<false>(src[4], src[5], 0); hh = pk8<true>(src[6], src[7], hh);
        *(int2v*)(WF8 + 32768 + (size_t)g * 8) = (int2v){lo, hh};
    }
    __syncthreads();

    float v = 0.f;
    if (u < 128) {
        const f32x4* hr = (const f32x4*)hL;
        const f32x4* wo = (const f32x4*)(Wo + (size_t)u * U_H);
        float s2 = 0.f;
#pragma unroll
        for (int i = 0; i < 64; ++i) {
            f32x4 a = hr[i], w = wo[i];
            s2 += a[0]*w[0] + a[1]*w[1] + a[2]*w[2] + a[3]*w[3];
        }
        s2 += bo[u];
        float x = xs[((size_t)b * T_LEN + T_LEN - 1) * D_IN + u];
        float diff = x - s2;
        v = diff * diff;
    }
#pragma unroll
    for (int o = 32; o > 0; o >>= 1) v += __shfl_down(v, o);
    if (u == 0) red[0] = v;
    if (u == 64) red[1] = v;
    __syncthreads();
    if (u == 0) part2[b] = red[0] + red[1];
}

// ---------------- kernel 1: main pipeline -- ROLLED ut-loop (R16/R21 exact) --
// 1024 blocks x 512 threads (8 waves), 1 tile (32 rows) per wave, M=32.
// Measured optimum of the session (59.95us total). Key ingredients:
//  - fp8 swapped-operand chain, dec in-register via cvt_pk + permlane32_swap
//  - all fragment state in named scalars (no spill; VGPR=60)
//  - rolled ut-loop keeps hot body I$-resident (~120 instrs)
//  - bias/bo folded into MFMA C-init; loss fused into epilogue
//  - one partial store per block; no hot atomics anywhere
__global__ __launch_bounds__(512, 2) void k_main(
        const float* __restrict__ xs, const float* __restrict__ budR,
        const float* __restrict__ boR, const char* __restrict__ WF8,
        float* __restrict__ part) {
    __shared__ __align__(16) char lds[67200];
    const int tid = threadIdx.x;

    for (int i = tid; i < 4096; i += 512)
        ((f32x4*)lds)[i] = ((const f32x4*)WF8)[i];
    const int b = blockIdx.x >> 4;          // 16 blocks per batch-entry
    if (tid < 64) ((f32x4*)(lds + 65536))[tid] = ((const f32x4*)(budR + b * 256))[tid];
    else if (tid < 96) ((f32x4*)(lds + 66560))[tid - 64] = ((const f32x4*)boR)[tid - 64];
    __syncthreads();

    const int wave = tid >> 6, lane = tid & 63;
    const int m = lane & 31, hi = lane >> 5;
    const float* xsb = xs + ((size_t)b << 19);
    const float* budL = (const float*)(lds + 65536);
    const float* boL  = (const float*)(lds + 66560);
    float* wsumf = (float*)(lds + 67072);

    const int tile = blockIdx.x * 8 + wave;
    const int t0 = (tile & 127) << 5;

    // ---- X row -> fp8 B-frags (8 named i64) ----
    const float* xrow = xsb + (size_t)(t0 + m) * 128 + hi * 8;
    i64 x0, x1, x2, x3, x4, x5, x6, x7;
    {
#define LDX(KS, XV)                                                      \
        {   f32x4 v0 = *(const f32x4*)(xrow + KS * 16);                  \
            f32x4 v1 = *(const f32x4*)(xrow + KS * 16 + 4);              \
            int lo = pk8<false>(v0[0], v0[1], 0); lo = pk8<true>(v0[2], v0[3], lo); \
            int hh = pk8<false>(v1[0], v1[1], 0); hh = pk8<true>(v1[2], v1[3], hh); \
            XV = __builtin_bit_cast(i64, (int2v){lo, hh}); }
        LDX(0, x0) LDX(1, x1) LDX(2, x2) LDX(3, x3)
        LDX(4, x4) LDX(5, x5) LDX(6, x6) LDX(7, x7)
#undef LDX
    }

    // ---- o accumulators init from boR (bo folded into GEMM2 C-init) ----
    f32x16 o0, o1, o2, o3;
#define OINIT(OV, DT)                                                    \
    {   const float* bp = boL + (DT) * 32 + hi * 16;                     \
        f32x4 b0 = *(const f32x4*)(bp), b1 = *(const f32x4*)(bp + 4);    \
        f32x4 b2 = *(const f32x4*)(bp + 8), b3 = *(const f32x4*)(bp + 12); \
        OV[0]=b0[0]; OV[1]=b0[1]; OV[2]=b0[2]; OV[3]=b0[3];              \
        OV[4]=b1[0]; OV[5]=b1[1]; OV[6]=b1[2]; OV[7]=b1[3];              \
        OV[8]=b2[0]; OV[9]=b2[1]; OV[10]=b2[2]; OV[11]=b2[3];            \
        OV[12]=b3[0]; OV[13]=b3[1]; OV[14]=b3[2]; OV[15]=b3[3]; }
    OINIT(o0, 0) OINIT(o1, 1) OINIT(o2, 2) OINIT(o3, 3)
#undef OINIT

    // ---- main rolled loop over ut ----
#pragma clang loop unroll(disable)
    for (int ut = 0; ut < 8; ++ut) {
        // ph1: C-init ca from budR (bias folded), cb = 0
        f32x16 ca, cb;
        {
            const float* bp = budL + ut * 32 + hi * 16;
            f32x4 b0 = *(const f32x4*)(bp), b1 = *(const f32x4*)(bp + 4);
            f32x4 b2 = *(const f32x4*)(bp + 8), b3 = *(const f32x4*)(bp + 12);
            ca[0]=b0[0]; ca[1]=b0[1]; ca[2]=b0[2]; ca[3]=b0[3];
            ca[4]=b1[0]; ca[5]=b1[1]; ca[6]=b1[2]; ca[7]=b1[3];
            ca[8]=b2[0]; ca[9]=b2[1]; ca[10]=b2[2]; ca[11]=b2[3];
            ca[12]=b3[0]; ca[13]=b3[1]; ca[14]=b3[2]; ca[15]=b3[3];
#pragma unroll
            for (int i = 0; i < 16; ++i) cb[i] = 0.f;
        }
        const char* wb = lds + ((ut * 8) << 9) + (lane << 3);
        ca = __builtin_amdgcn_mfma_f32_32x32x16_fp8_fp8(*(const i64*)(wb + 0*512), x0, ca, 0,0,0);
        cb = __builtin_amdgcn_mfma_f32_32x32x16_fp8_fp8(*(const i64*)(wb + 1*512), x1, cb, 0,0,0);
        ca = __builtin_amdgcn_mfma_f32_32x32x16_fp8_fp8(*(const i64*)(wb + 2*512), x2, ca, 0,0,0);
        cb = __builtin_amdgcn_mfma_f32_32x32x16_fp8_fp8(*(const i64*)(wb + 3*512), x3, cb, 0,0,0);
        ca = __builtin_amdgcn_mfma_f32_32x32x16_fp8_fp8(*(const i64*)(wb + 4*512), x4, ca, 0,0,0);
        cb = __builtin_amdgcn_mfma_f32_32x32x16_fp8_fp8(*(const i64*)(wb + 5*512), x5, cb, 0,0,0);
        ca = __builtin_amdgcn_mfma_f32_32x32x16_fp8_fp8(*(const i64*)(wb + 6*512), x6, ca, 0,0,0);
        cb = __builtin_amdgcn_mfma_f32_32x32x16_fp8_fp8(*(const i64*)(wb + 7*512), x7, cb, 0,0,0);

        // relu + fp8 pack + permlane32_swap -> dec frags for uk=2ut, 2ut+1
        i64 dlo, dhi;
        {
            f32x16 c;
#pragma unroll
            for (int i = 0; i < 16; ++i) c[i] = fmaxf(ca[i] + cb[i], 0.f);
            int d0 = pk8<false>(c[0],  c[1],  0); d0 = pk8<true>(c[2],  c[3],  d0);
            int d1 = pk8<false>(c[4],  c[5],  0); d1 = pk8<true>(c[6],  c[7],  d1);
            int d2 = pk8<false>(c[8],  c[9],  0); d2 = pk8<true>(c[10], c[11], d2);
            int d3 = pk8<false>(c[12], c[13], 0); d3 = pk8<true>(c[14], c[15], d3);
            int2v s = __builtin_amdgcn_permlane32_swap(d0, d1, false, false);
            int2v t = __builtin_amdgcn_permlane32_swap(d2, d3, false, false);
            dlo = __builtin_bit_cast(i64, s);
            dhi = __builtin_bit_cast(i64, t);
        }

        // ph2: weights for uk=2ut (dlo) and uk=2ut+1 (dhi), 4 dt each
        const char* w2 = lds + 32768 + ((ut * 8) << 9) + (lane << 3);
        o0 = __builtin_amdgcn_mfma_f32_32x32x16_fp8_fp8(*(const i64*)(w2 + 0*512), dlo, o0, 0,0,0);
        o1 = __builtin_amdgcn_mfma_f32_32x32x16_fp8_fp8(*(const i64*)(w2 + 1*512), dlo, o1, 0,0,0);
        o2 = __builtin_amdgcn_mfma_f32_32x32x16_fp8_fp8(*(const i64*)(w2 + 2*512), dlo, o2, 0,0,0);
        o3 = __builtin_amdgcn_mfma_f32_32x32x16_fp8_fp8(*(const i64*)(w2 + 3*512), dlo, o3, 0,0,0);
        o0 = __builtin_amdgcn_mfma_f32_32x32x16_fp8_fp8(*(const i64*)(w2 + 4*512), dhi, o0, 0,0,0);
        o1 = __builtin_amdgcn_mfma_f32_32x32x16_fp8_fp8(*(const i64*)(w2 + 5*512), dhi, o1, 0,0,0);
        o2 = __builtin_amdgcn_mfma_f32_32x32x16_fp8_fp8(*(const i64*)(w2 + 6*512), dhi, o2, 0,0,0);
        o3 = __builtin_amdgcn_mfma_f32_32x32x16_fp8_fp8(*(const i64*)(w2 + 7*512), dhi, o3, 0,0,0);
    }

    // ---- fused loss epilogue (bo already inside o) ----
    const int t = t0 + m;
    const float sel = (t > 0) ? 1.f : 0.f;
    const float* trow = xsb + (size_t)((t > 0) ? t - 1 : 0) * 128;
    float lacc = 0.f;
#define EPI(OV, DT)                                                      \
    {   _Pragma("unroll")                                                \
        for (int q = 0; q < 4; ++q) {                                    \
            f32x4 tg = *(const f32x4*)(trow + (DT) * 32 + q * 8 + hi * 4); \
            _Pragma("unroll")                                            \
            for (int j = 0; j < 4; ++j) {                                \
                float diff = tg[j] - OV[q * 4 + j];                      \
                lacc += sel * diff * diff;                               \
            }                                                            \
        }                                                                \
    }
    EPI(o0, 0) EPI(o1, 1) EPI(o2, 2) EPI(o3, 3)
#undef EPI

    // ---- block-level reduction: ONE store per block, no atomic ----
#pragma unroll
    for (int o = 32; o > 0; o >>= 1) lacc += __shfl_down(lacc, o);
    if (lane == 0) wsumf[wave] = lacc;
    __syncthreads();
    if (tid == 0) {
        float s = 0.f;
#pragma unroll
        for (int i = 0; i < 8; ++i) s += wsumf[i];
        part[blockIdx.x] = s;
    }
}

// ---------------- kernel 2: final reduction (plain store, no atomic) ---------
__global__ void k_final(const float* __restrict__ part, const float* __restrict__ part2,
                        float* __restrict__ loss) {
    __shared__ float ws[16];
    const int tid = threadIdx.x;   // 1024
    float v = part[tid];
    if (tid < 64) v += part2[tid];
#pragma unroll
    for (int o = 32; o > 0; o >>= 1) v += __shfl_down(v, o);
    if ((tid & 63) == 0) ws[tid >> 6] = v;
    __syncthreads();
    if (tid == 0) {
        float s = 0.f;
#pragma unroll
        for (int i = 0; i < 16; ++i) s += ws[i];
        *loss = s * (1.f / 262144.f);
    }
}

extern "C" void kernel_launch(void* const* d_in, const int* in_sizes, int n_in,
                              void* d_out, int out_size, void* d_ws, size_t ws_size,
                              hipStream_t stream) {
    const float* xs = (const float*)d_in[0];
    const float* We = (const float*)d_in[1];
    const float* be = (const float*)d_in[2];
    // d_in[3] = ue (unused: encoder hidden state is always zero)
    const float* Wd = (const float*)d_in[4];
    const float* bd = (const float*)d_in[5];
    const float* ud = (const float*)d_in[6];
    const float* Wo = (const float*)d_in[7];
    const float* bo = (const float*)d_in[8];
    float* loss = (float*)d_out;

    char* ws = (char*)d_ws;
    float* budR  = (float*)(ws);             // 65536 B
    char*  WF8   = (char*)(ws + 65536);      // 65536 B
    float* boR   = (float*)(ws + 131072);    // 512 B
    float* part  = (float*)(ws + 131584);    // 4096 B (1024 block partials)
    float* part2 = (float*)(ws + 135680);    // 256 B  (64 loss0 partials)

    k_pre<<<64, 256, 0, stream>>>(xs, We, be, Wd, bd, ud, Wo, bo,
                                  budR, boR, WF8, part2);
    k_main<<<1024, 512, 0, stream>>>(xs, budR, boR, WF8, part);
    k_final<<<1, 1024, 0, stream>>>(part, part2, loss);
}